// Round 3
// baseline (83.706 us; speedup 1.0000x reference)
//
#include <hip/hip_runtime.h>

#define N 8192
#define DIM 64

typedef float f32x4 __attribute__((ext_vector_type(4)));
typedef short bf16x8 __attribute__((ext_vector_type(8)));

__device__ __forceinline__ unsigned short f32_to_bf16_rne(float f) {
  unsigned int u = __float_as_uint(f);
  unsigned int r = (u + 0x7FFFu + ((u >> 16) & 1u)) >> 16;
  return (unsigned short)r;
}

// x (f32 [N][64]) -> xb (bf16 [N][64]); 131072 threads, 4 elems each
__global__ void cvt_kernel(const float* __restrict__ x, unsigned short* __restrict__ xb) {
  int gid = blockIdx.x * blockDim.x + threadIdx.x;
  float4 v = reinterpret_cast<const float4*>(x)[gid];
  ushort4 o;
  o.x = f32_to_bf16_rne(v.x);
  o.y = f32_to_bf16_rne(v.y);
  o.z = f32_to_bf16_rne(v.z);
  o.w = f32_to_bf16_rne(v.w);
  reinterpret_cast<ushort4*>(xb)[gid] = o;
}

// Grid: 1024 blocks = 128 row-groups x 8 j-chunks, 256 threads (4 waves).
// Wave w: rows i0w..i0w+15, cols jbase..jbase+1023, in 8 sub-chunks of 128 j.
// Per sub-chunk: G-phase (MFMA -> ds_write_b128 into per-wave G[16][132]),
// A-phase (contiguous dwordx4 A loads: 2 rows x 512B per inst; G via ds_read_b128).
__global__ __launch_bounds__(256, 4) void main_kernel(
    const float* __restrict__ A,
    const unsigned short* __restrict__ xb,
    float* __restrict__ spart) {
  int bid = blockIdx.x;
  int rg = bid & 127;
  int js = bid >> 7;
  int tid = threadIdx.x;
  int w = tid >> 6;
  int lane = tid & 63;
  int i0w = rg * 64 + w * 16;
  int jbase = js * 1024;
  int c = lane & 15;   // operand row selector; G column (i)
  int q = lane >> 4;   // k-quad; G row group (j)
  int h = lane >> 5;   // A-phase: row parity
  int m = lane & 31;   // A-phase: col-quad selector

  __shared__ alignas(16) float G[4][16][132];  // [wave][i][j+pad]

  // xi fragments (B-operand): rows i0w + c
  const unsigned short* pxi = xb + (size_t)(i0w + c) * DIM + q * 8;
  bf16x8 xi0 = *reinterpret_cast<const bf16x8*>(pxi);
  bf16x8 xi1 = *reinterpret_cast<const bf16x8*>(pxi + 32);

  float sacc[8] = {0.f, 0.f, 0.f, 0.f, 0.f, 0.f, 0.f, 0.f};
  f32x4 a_buf[8];

  // A-phase base: row i0w + h, col jbase + m*4; inst a adds rows a*2, sub-chunk adds cc*128
  const float* pA = A + (size_t)(i0w + h) * N + jbase + m * 4;

  // prologue: issue sub-chunk 0 A-loads
#pragma unroll
  for (int a = 0; a < 8; ++a)
    a_buf[a] = *reinterpret_cast<const f32x4*>(pA + (size_t)(a * 2) * N);

  for (int cc = 0; cc < 8; ++cc) {
    int jc = jbase + cc * 128;

    // ---- G-phase: compute G[j'][i] for j' in [0,128), store [i][j'] ----
#pragma unroll
    for (int jt = 0; jt < 8; ++jt) {
      const unsigned short* pj = xb + (size_t)(jc + jt * 16 + c) * DIM + q * 8;
      bf16x8 xj0 = *reinterpret_cast<const bf16x8*>(pj);
      bf16x8 xj1 = *reinterpret_cast<const bf16x8*>(pj + 32);
      f32x4 g = {0.f, 0.f, 0.f, 0.f};
      g = __builtin_amdgcn_mfma_f32_16x16x32_bf16(xj0, xi0, g, 0, 0, 0);
      g = __builtin_amdgcn_mfma_f32_16x16x32_bf16(xj1, xi1, g, 0, 0, 0);
      // lane (q,c) holds G[j' = jt*16+q*4+v][i = c], v=0..3 -> contiguous in [i][j']
      *reinterpret_cast<f32x4*>(&G[w][c][jt * 16 + q * 4]) = g;
    }

    // ---- A-phase: inst a covers rows i0w+a*2+h, cols jc + m*4 .. +3 ----
#pragma unroll
    for (int a = 0; a < 8; ++a) {
      f32x4 g4 = *reinterpret_cast<const f32x4*>(&G[w][a * 2 + h][m * 4]);
      f32x4 a4 = a_buf[a];
      float s = sacc[a];
      s = fmaf(a4[0], g4[0], s);
      s = fmaf(a4[1], g4[1], s);
      s = fmaf(a4[2], g4[2], s);
      s = fmaf(a4[3], g4[3], s);
      sacc[a] = s;
    }

    // ---- prefetch next sub-chunk's A ----
    if (cc < 7) {
      const float* pAn = pA + (cc + 1) * 128;
#pragma unroll
      for (int a = 0; a < 8; ++a)
        a_buf[a] = *reinterpret_cast<const f32x4*>(pAn + (size_t)(a * 2) * N);
    }
  }

  // Reduce over the 32-lane group (cols), rows a*2+h stay lane-local
#pragma unroll
  for (int a = 0; a < 8; ++a) {
    float s = sacc[a];
    s += __shfl_xor(s, 1);
    s += __shfl_xor(s, 2);
    s += __shfl_xor(s, 4);
    s += __shfl_xor(s, 8);
    s += __shfl_xor(s, 16);
    sacc[a] = s;
  }
  if (m == 0) {
#pragma unroll
    for (int a = 0; a < 8; ++a)
      spart[(size_t)js * N + i0w + a * 2 + h] = sacc[a];
  }
}

// out[i][d] = 1 - 0.1*x[i][d] - 0.01*sum_c spart[c][i]; 131072 threads, 4 elems each
__global__ void finish_kernel(const float* __restrict__ x,
                              const float* __restrict__ spart,
                              float* __restrict__ out) {
  int gid = blockIdx.x * blockDim.x + threadIdx.x;
  float4 xv = reinterpret_cast<const float4*>(x)[gid];
  int i = gid >> 4;  // (gid*4)/64
  float s = 0.f;
#pragma unroll
  for (int cc = 0; cc < 8; ++cc) s += spart[(size_t)cc * N + i];
  float4 o;
  o.x = 1.0f - 0.1f * xv.x - 0.01f * s;
  o.y = 1.0f - 0.1f * xv.y - 0.01f * s;
  o.z = 1.0f - 0.1f * xv.z - 0.01f * s;
  o.w = 1.0f - 0.1f * xv.w - 0.01f * s;
  reinterpret_cast<float4*>(out)[gid] = o;
}

extern "C" void kernel_launch(void* const* d_in, const int* in_sizes, int n_in,
                              void* d_out, int out_size, void* d_ws, size_t ws_size,
                              hipStream_t stream) {
  // d_in[0] = t (unused), d_in[1] = x f32 [8192][64], d_in[2] = A f32 [8192][8192]
  const float* x = (const float*)d_in[1];
  const float* A = (const float*)d_in[2];
  float* out = (float*)d_out;

  unsigned short* xb = (unsigned short*)d_ws;                  // 1 MB bf16 x
  float* spart = (float*)((char*)d_ws + (size_t)N * DIM * 2);  // 256 KB partials

  cvt_kernel<<<512, 256, 0, stream>>>(x, xb);
  main_kernel<<<1024, 256, 0, stream>>>(A, xb, spart);
  finish_kernel<<<512, 256, 0, stream>>>(x, spart, out);
}